// Round 19
// baseline (744.092 us; speedup 1.0000x reference)
//
#include <hip/hip_runtime.h>
#include <math.h>

typedef unsigned short u16;
typedef unsigned long long u64;
typedef __attribute__((ext_vector_type(4))) float f32x4;
typedef __attribute__((ext_vector_type(16))) float f32x16;
typedef __attribute__((ext_vector_type(8))) __bf16 bf16x8;

#define GLDS16(g, l) __builtin_amdgcn_global_load_lds(                        \
    (const __attribute__((address_space(1))) void*)(g),                       \
    (__attribute__((address_space(3))) void*)(l), 16, 0, 0)

__device__ __forceinline__ u16 f2b(float x){
  unsigned u = __float_as_uint(x);
  u = (u + 0x7FFFu + ((u >> 16) & 1u)) >> 16;
  return (u16)u;
}
__device__ __forceinline__ float b2f(u16 u){ return __uint_as_float(((unsigned)u) << 16); }
__device__ __forceinline__ f32x4 zero4(){ f32x4 v; v[0]=0.f; v[1]=0.f; v[2]=0.f; v[3]=0.f; return v; }
__device__ __forceinline__ float sigm(float x){ return 1.f/(1.f+expf(-x)); }

// ---------------- combined prep: f2b(W_ih), f2b(W_hh), bias4, init, gather --
__global__ __launch_bounds__(256) void k_prep(
    const float* __restrict__ W_ih, u16* __restrict__ W_ih_b,
    const float* __restrict__ W_hh, u16* __restrict__ W_hh_b,
    const float* __restrict__ bih, const float* __restrict__ bhh,
    float* __restrict__ b4,
    const float* __restrict__ h_in, u16* __restrict__ hb0,
    const int* __restrict__ x, const float* __restrict__ emb,
    u16* __restrict__ e_seq)
{
  int g = blockIdx.x, tid = threadIdx.x;
  if (g < 128){
    size_t base = ((size_t)g*256 + tid)*4;
    size_t stride = (size_t)128*256*4;
    for (size_t i = base; i < 2097152UL; i += stride){
      float4 v = *(const float4*)(W_ih + i);
      W_ih_b[i] = f2b(v.x); W_ih_b[i+1] = f2b(v.y);
      W_ih_b[i+2] = f2b(v.z); W_ih_b[i+3] = f2b(v.w);
    }
    for (size_t i = base; i < 4194304UL; i += stride){
      float4 v = *(const float4*)(W_hh + i);
      W_hh_b[i] = f2b(v.x); W_hh_b[i+1] = f2b(v.y);
      W_hh_b[i+2] = f2b(v.z); W_hh_b[i+3] = f2b(v.w);
    }
  } else if (g < 136){
    int i = (g - 128)*256 + tid;            // 0..2047
    b4[i*2]   = bih[i*2]   + bhh[i*2];
    b4[i*2+1] = bih[i*2+1] + bhh[i*2+1];
#pragma unroll
    for (int k = 0; k < 16; ++k){
      int idx = i*16 + k;
      hb0[idx] = f2b(h_in[idx]);
    }
  } else {
    for (int row = g - 136; row < 2048; row += 376){
      int xi = x[row];
      const float* er = emb + (size_t)xi*512;
      u16* dr = e_seq + (size_t)row*512;
      for (int k = tid; k < 512; k += 256) dr[k] = f2b(er[k]);
    }
  }
}

// ---------------- 256x256 tile GEMM, 32x32x16 MFMA, REG-STAGED -------------
// Global -> VGPR (double-buffered) -> 8B-swizzled ds_write_b64 -> single
// 64KB LDS buffer -> conflict-free ds_read_b64 pairs (slot ^= row&15:
// 32 lanes spread over 16 slots x 2 rows = 2-way aliasing = free, m136).
// Two raw barriers + lgkmcnt(0) per tile; prefetch depth 1 in registers
// (compiler-managed vmcnt for reg deps). Write and read use the SAME
// involution inside the kernel (no GLDS source-coupling).
// C/D layout (verified): col=lane&31, row=(r&3)+8(r>>2)+4*hi.
template<int EPI>
__global__ __launch_bounds__(512, 1) void gemm256(
    const u16* __restrict__ A, const u16* __restrict__ B,
    const float* __restrict__ bias, u16* __restrict__ C,
    int K, int ldc, int nmt, float* __restrict__ pp)
{
  __shared__ u16 sA[256*64];
  __shared__ u16 sB[256*64];
  int nwg = gridDim.x;                 // multiple of 8
  int qq = nwg >> 3;
  int xcd = blockIdx.x & 7, idx = blockIdx.x >> 3;
  int wg = xcd*qq + idx;               // bijective XCD chunking
  int mt = wg % nmt, nt = wg / nmt;    // mt fast: consecutive blocks share B
  int m0 = mt*256, n0 = nt*256;
  int tid = threadIdx.x, lane = tid & 63, w = tid >> 6;
  int wr = w >> 2, wc = w & 3;         // wave grid 2(M) x 4(N)
  int l31 = lane & 31, hi = lane >> 5;
  int qr = (w & 1) << 1;               // q rotation per wave parity

  int ra = tid >> 1, ha = tid & 1;     // staging: row, 32-col half
  int r15 = ra & 15;

  uint4 a4A[4], b4A[4], a4B[4], b4B[4];

#define LOADG(A4, B4, t) do{                                                  \
    const u16* _pa = A + (size_t)(m0 + ra)*K + (t)*64 + ha*32;                \
    const u16* _pb = B + (size_t)(n0 + ra)*K + (t)*64 + ha*32;                \
    A4[0] = *(const uint4*)(_pa);      A4[1] = *(const uint4*)(_pa + 8);      \
    A4[2] = *(const uint4*)(_pa + 16); A4[3] = *(const uint4*)(_pa + 24);     \
    B4[0] = *(const uint4*)(_pb);      B4[1] = *(const uint4*)(_pb + 8);      \
    B4[2] = *(const uint4*)(_pb + 16); B4[3] = *(const uint4*)(_pb + 24);     \
  }while(0)

#define DSW1(dst, R4, i) do{                                                  \
    int _s = ((ha*8 + (i)*2) ^ r15) << 2;                                     \
    *(u64*)&dst[ra*64 + _s]       = ((u64)R4[i].y << 32) | R4[i].x;           \
    *(u64*)&dst[ra*64 + (_s ^ 4)] = ((u64)R4[i].w << 32) | R4[i].z;           \
  }while(0)

#define DSW(A4, B4) do{                                                      \
    DSW1(sA, A4, 0); DSW1(sA, A4, 1); DSW1(sA, A4, 2); DSW1(sA, A4, 3);      \
    DSW1(sB, B4, 0); DSW1(sB, B4, 1); DSW1(sB, B4, 2); DSW1(sB, B4, 3);      \
  }while(0)

  f32x16 acc[4][2];
#pragma unroll
  for (int m = 0; m < 4; ++m)
#pragma unroll
    for (int n = 0; n < 2; ++n)
#pragma unroll
      for (int r = 0; r < 16; ++r) acc[m][n][r] = 0.f;

  union U8 { u64 q[2]; bf16x8 v; };

#define MFMA_TILE() do{                                                       \
    __builtin_amdgcn_s_setprio(1);                                            \
    _Pragma("unroll")                                                         \
    for (int qi = 0; qi < 4; ++qi){                                           \
      int q = (qi + qr) & 3;                                                  \
      int sl0 = q*4 + hi*2;            /* even */                             \
      bf16x8 av[4], bv[2];                                                    \
      _Pragma("unroll")                                                       \
      for (int m = 0; m < 4; ++m){                                            \
        int row = wr*128 + m*32 + l31;                                        \
        int sp = (sl0 ^ (row & 15)) << 2;                                     \
        U8 u; u.q[0] = *(const u64*)&sA[row*64 + sp];                         \
              u.q[1] = *(const u64*)&sA[row*64 + (sp ^ 4)];                   \
        av[m] = u.v;                                                          \
      }                                                                       \
      _Pragma("unroll")                                                       \
      for (int n = 0; n < 2; ++n){                                            \
        int brow = wc*64 + n*32 + l31;                                        \
        int sp = (sl0 ^ (brow & 15)) << 2;                                    \
        U8 u; u.q[0] = *(const u64*)&sB[brow*64 + sp];                        \
              u.q[1] = *(const u64*)&sB[brow*64 + (sp ^ 4)];                  \
        bv[n] = u.v;                                                          \
      }                                                                       \
      _Pragma("unroll")                                                       \
      for (int m = 0; m < 4; ++m)                                             \
        _Pragma("unroll")                                                     \
        for (int n = 0; n < 2; ++n)                                           \
          acc[m][n] = __builtin_amdgcn_mfma_f32_32x32x16_bf16(av[m], bv[n], acc[m][n], 0, 0, 0); \
    }                                                                         \
    __builtin_amdgcn_s_setprio(0);                                            \
  }while(0)

#define ITER(CA, CB, NA, NB, t, PF) do{                                       \
    if (PF) LOADG(NA, NB, (t)+1);                                             \
    DSW(CA, CB);                                                              \
    asm volatile("s_waitcnt lgkmcnt(0)" ::: "memory");                        \
    __builtin_amdgcn_s_barrier();                                             \
    asm volatile("" ::: "memory");                                            \
    MFMA_TILE();                                                              \
    asm volatile("" ::: "memory");                                            \
    __builtin_amdgcn_s_barrier();                                             \
    asm volatile("" ::: "memory");                                            \
  }while(0)

  int T = K >> 6;                      // even, >= 4
  LOADG(a4A, b4A, 0);
  int t = 0;
  for (; t + 2 < T; t += 2){
    ITER(a4A, b4A, a4B, b4B, t,   1);
    ITER(a4B, b4B, a4A, b4A, t+1, 1);
  }
  ITER(a4A, b4A, a4B, b4B, T-2, 1);
  ITER(a4B, b4B, a4A, b4A, T-1, 0);

#undef ITER
#undef MFMA_TILE
#undef DSW
#undef DSW1
#undef LOADG

#pragma unroll
  for (int m = 0; m < 4; ++m){
    float es16[16];
    if (EPI == 3){
#pragma unroll
      for (int r = 0; r < 16; ++r) es16[r] = 0.f;
    }
#pragma unroll
    for (int n = 0; n < 2; ++n){
      int ccol = n0 + wc*64 + n*32 + l31;
      float bv2 = bias ? bias[ccol] : 0.f;
#pragma unroll
      for (int r = 0; r < 16; ++r){
        int crow = m0 + wr*128 + m*32 + (r & 3) + 8*(r >> 2) + 4*hi;
        float v = acc[m][n][r] + bv2;
        C[(size_t)crow*ldc + ccol] = f2b(v);
        if (EPI == 3) es16[r] += expf(v);
      }
    }
    if (EPI == 3){
      int npart = (nwg / nmt) * 4;
#pragma unroll
      for (int r = 0; r < 16; ++r){
        float s = es16[r];
        s += __shfl_xor(s, 1); s += __shfl_xor(s, 2); s += __shfl_xor(s, 4);
        s += __shfl_xor(s, 8); s += __shfl_xor(s, 16);
        es16[r] = s;
      }
      if (l31 == 0){
#pragma unroll
        for (int r = 0; r < 16; ++r){
          int row = m0 + wr*128 + m*32 + (r & 3) + 8*(r >> 2) + 4*hi;
          pp[(size_t)row*npart + nt*4 + wc] = es16[r];
        }
      }
    }
  }
}

// ---------------- 128x128 GEMM (round-8 version) ---------------------------
template<int EPI>
__global__ __launch_bounds__(256) void gemm_bt(
    const u16* __restrict__ A, const u16* __restrict__ B,
    const float* __restrict__ bias, void* __restrict__ Cv,
    int K, int ldc, int nmt, float* __restrict__ pp)
{
  __shared__ u16 sA[2][128*32];
  __shared__ u16 sB[2][128*32];
  int nwg = gridDim.x;
  int qq = nwg >> 3, rr8 = nwg & 7;
  int xcd = blockIdx.x & 7, idx = blockIdx.x >> 3;
  int wg = (xcd < rr8 ? xcd*(qq+1) : rr8*(qq+1) + (xcd - rr8)*qq) + idx;
  int mt = wg % nmt, nt = wg / nmt;
  int m0 = mt*128, n0 = nt*128;
  int tid = threadIdx.x, lane = tid & 63, wid = tid >> 6;
  int q = lane & 3, rr = lane >> 2;
  int c0 = wid*2, c1 = wid*2+1;
  int sq = rr & 3;
  const u16* gA0 = A + (size_t)(m0 + c0*16 + rr)*K + ((q ^ sq)*8);
  const u16* gA1 = A + (size_t)(m0 + c1*16 + rr)*K + ((q ^ sq)*8);
  const u16* gB0 = B + (size_t)(n0 + c0*16 + rr)*K + ((q ^ sq)*8);
  const u16* gB1 = B + (size_t)(n0 + c1*16 + rr)*K + ((q ^ sq)*8);
  f32x4 acc[4][4];
#pragma unroll
  for (int m=0;m<4;++m)
#pragma unroll
    for (int n=0;n<4;++n) acc[m][n] = zero4();
  int wr = wid >> 1, wc = wid & 1;
  int lr = lane & 15, ks = lane >> 4;
  int rdoff = (ks ^ (lr & 3)) * 8;

#define STAGEG(buf, k0) do{                                                   \
    GLDS16(gA0 + (k0), sA[buf] + c0*512);                                     \
    GLDS16(gA1 + (k0), sA[buf] + c1*512);                                     \
    GLDS16(gB0 + (k0), sB[buf] + c0*512);                                     \
    GLDS16(gB1 + (k0), sB[buf] + c1*512);                                     \
  }while(0)

  STAGEG(0, 0);
  asm volatile("s_waitcnt vmcnt(0)" ::: "memory");
  __syncthreads();
  int cur = 0;
  for (int k0 = 0; k0 < K; k0 += 32){
    if (k0 + 32 < K) STAGEG(cur^1, k0 + 32);
    bf16x8 af[4], bfr[4];
#pragma unroll
    for (int m=0;m<4;++m) af[m]  = *(const bf16x8*)&sA[cur][(wr*64 + m*16 + lr)*32 + rdoff];
#pragma unroll
    for (int n=0;n<4;++n) bfr[n] = *(const bf16x8*)&sB[cur][(wc*64 + n*16 + lr)*32 + rdoff];
#pragma unroll
    for (int m=0;m<4;++m)
#pragma unroll
      for (int n=0;n<4;++n)
        acc[m][n] = __builtin_amdgcn_mfma_f32_16x16x32_bf16(af[m], bfr[n], acc[m][n], 0, 0, 0);
    asm volatile("s_waitcnt vmcnt(0)" ::: "memory");
    __syncthreads();
    cur ^= 1;
  }
#undef STAGEG

#pragma unroll
  for (int m=0;m<4;++m){
    int crow = m0 + wr*64 + m*16 + ks*4;
#pragma unroll
    for (int n=0;n<4;++n){
      int ccol = n0 + wc*64 + n*16 + lr;
      float bv = bias ? bias[ccol] : 0.f;
#pragma unroll
      for (int r=0;r<4;++r){
        float v = acc[m][n][r] + bv;
        if (EPI == 1) v = tanhf(v);
        ((u16*)Cv)[(size_t)(crow + r)*ldc + ccol] = f2b(v);
      }
    }
  }
}

// ---------------- fused: LSTM (64 blocks) + streaming f2b helpers ---------
// (round-18 champion body, unchanged)
__global__ __launch_bounds__(256, 1) void k_fused(
    const u16* __restrict__ pre,   // [2048][4096] bf16
    const u16* __restrict__ Whh,   // [4096][1024] bf16
    const float* __restrict__ c_in,// [32][1024] fp32
    u16* __restrict__ h0buf,       // [32][1024] bf16 ping (holds h_0)
    u16* __restrict__ h1buf,       // pong
    u16* __restrict__ concat,      // [2048][2048] bf16; cols 0..1023 <- h_t
    float* __restrict__ h_out,     // [32][1024] fp32 final h
    float* __restrict__ c_out,     // [32][1024] fp32 final c
    int* __restrict__ flags,       // [64*32] zeroed per launch (128B/rank)
    const float* __restrict__ W_o, u16* __restrict__ W_o_b,
    const float* __restrict__ W_a, u16* __restrict__ W_a_b,
    const float* __restrict__ ctx, u16* __restrict__ ctx_b)
{
  __shared__ u16 sA[32*1024];
  int tid = threadIdx.x;
  int g = blockIdx.x;

  if (g >= 64){
    int hb2 = g - 64;                        // 0..191
    size_t stride = (size_t)192*256*4;
    size_t base = ((size_t)hb2*256 + tid)*4;
    for (size_t i = base; i < 32768000UL; i += stride){
      float4 v = *(const float4*)(W_o + i);
      u16 o0 = f2b(v.x), o1 = f2b(v.y), o2 = f2b(v.z), o3 = f2b(v.w);
      W_o_b[i] = o0; W_o_b[i+1] = o1; W_o_b[i+2] = o2; W_o_b[i+3] = o3;
    }
    for (size_t i = base; i < 2097152UL; i += stride){
      float4 v = *(const float4*)(W_a + i);
      u16 o0 = f2b(v.x), o1 = f2b(v.y), o2 = f2b(v.z), o3 = f2b(v.w);
      W_a_b[i] = o0; W_a_b[i+1] = o1; W_a_b[i+2] = o2; W_a_b[i+3] = o3;
    }
    for (size_t i = base; i < 2097152UL; i += stride){
      float4 v = *(const float4*)(ctx + i);
      u16 o0 = f2b(v.x), o1 = f2b(v.y), o2 = f2b(v.z), o3 = f2b(v.w);
      ctx_b[i] = o0; ctx_b[i+1] = o1; ctx_b[i+2] = o2; ctx_b[i+3] = o3;
    }
    return;
  }

  int w = tid >> 6, lane = tid & 63;
  int n = (g << 2) + w;            // 0..255
  int lr = lane & 15, ks = lane >> 4;

  bf16x8 breg[32];
  {
    const u16* wrow = Whh + (size_t)((lr>>2)*1024 + (n<<2) + (lr&3))*1024 + ks*8;
#pragma unroll
    for (int q2 = 0; q2 < 32; ++q2) breg[q2] = *(const bf16x8*)(wrow + q2*32);
  }
  int pb = lane & 31, dp = lane >> 5;
  int hcol = (n << 2) + dp*2;
  float c0r = c_in[pb*1024 + hcol];
  float c1r = c_in[pb*1024 + hcol + 1];

  int srow = tid >> 3, tc = tid & 7;   // staging: 8 threads per h row, 256B each
  float* gbuf = (float*)sA + w*544;    // per-wave 32x17-stride gate buffer
  const int* myflag = flags + lane*32; // one 128B line per rank

  for (int t = 0; t < 64; ++t){
    const u16* hin = (t & 1) ? h1buf : h0buf;
    u16* hout      = (t & 1) ? h0buf : h1buf;
    const u16* prow = pre + (size_t)(t*32)*4096 + (lr>>2)*1024 + (n<<2) + (lr&3);
    u16 pr0[4], pr1[4];
#pragma unroll
    for (int r2 = 0; r2 < 4; ++r2){
      int b0 = (ks<<2) + r2;
      pr0[r2] = prow[(size_t)b0*4096];
      pr1[r2] = prow[(size_t)(16+b0)*4096];
    }
    if (t && w == 0){
      int cap = 0;
      while (__hip_atomic_load(myflag, __ATOMIC_RELAXED, __HIP_MEMORY_SCOPE_AGENT) < t
             && ++cap < (1<<24))
        __builtin_amdgcn_s_sleep(1);
    }
    __syncthreads();             // wave 0 confirmed all 64 flags >= t
    u64 t0[16], t1[16];
#pragma unroll
    for (int j = 0; j < 16; ++j){
      const u64* src = (const u64*)(hin + srow*1024 + tc*8 + j*64);
      t0[j] = __hip_atomic_load(src,     __ATOMIC_RELAXED, __HIP_MEMORY_SCOPE_AGENT);
      t1[j] = __hip_atomic_load(src + 1, __ATOMIC_RELAXED, __HIP_MEMORY_SCOPE_AGENT);
    }
#pragma unroll
    for (int j = 0; j < 8; ++j){
      int kc = tc*8 + j*64;
      int dk = kc ^ ((srow & 7) << 3);
      ulonglong2 v2; v2.x = t0[j]; v2.y = t1[j];
      *(ulonglong2*)&sA[srow*1024 + dk] = v2;
    }
    __syncthreads();
    f32x4 acc0 = zero4(), acc1 = zero4();
#pragma unroll
    for (int q2 = 0; q2 < 16; ++q2){
      int ka = ((q2<<5) + (ks<<3)) ^ ((lr & 7) << 3);
      bf16x8 a0 = *(const bf16x8*)&sA[lr*1024 + ka];
      bf16x8 a1 = *(const bf16x8*)&sA[(16+lr)*1024 + ka];
      acc0 = __builtin_amdgcn_mfma_f32_16x16x32_bf16(a0, breg[q2], acc0, 0, 0, 0);
      acc1 = __builtin_amdgcn_mfma_f32_16x16x32_bf16(a1, breg[q2], acc1, 0, 0, 0);
    }
#pragma unroll
    for (int j = 8; j < 16; ++j){
      int kc = tc*8 + j*64;
      int dk = kc ^ ((srow & 7) << 3);
      ulonglong2 v2; v2.x = t0[j]; v2.y = t1[j];
      *(ulonglong2*)&sA[srow*1024 + dk] = v2;
    }
    __syncthreads();
#pragma unroll
    for (int q2 = 16; q2 < 32; ++q2){
      int ka = ((q2<<5) + (ks<<3)) ^ ((lr & 7) << 3);
      bf16x8 a0 = *(const bf16x8*)&sA[lr*1024 + ka];
      bf16x8 a1 = *(const bf16x8*)&sA[(16+lr)*1024 + ka];
      acc0 = __builtin_amdgcn_mfma_f32_16x16x32_bf16(a0, breg[q2], acc0, 0, 0, 0);
      acc1 = __builtin_amdgcn_mfma_f32_16x16x32_bf16(a1, breg[q2], acc1, 0, 0, 0);
    }
    __syncthreads();
#pragma unroll
    for (int r2 = 0; r2 < 4; ++r2){
      int b0 = (ks<<2) + r2;
      gbuf[b0*17 + lr]      = acc0[r2] + b2f(pr0[r2]);
      gbuf[(16+b0)*17 + lr] = acc1[r2] + b2f(pr1[r2]);
    }
    __syncthreads();
    unsigned hp;
    {
      int d0 = dp*2;
      float iA = gbuf[pb*17 + d0],      iB = gbuf[pb*17 + d0 + 1];
      float fA = gbuf[pb*17 + 4 + d0],  fB = gbuf[pb*17 + 5 + d0];
      float gA = gbuf[pb*17 + 8 + d0],  gB = gbuf[pb*17 + 9 + d0];
      float oA = gbuf[pb*17 + 12 + d0], oB = gbuf[pb*17 + 13 + d0];
      float cnA = sigm(fA)*c0r + sigm(iA)*tanhf(gA);
      float cnB = sigm(fB)*c1r + sigm(iB)*tanhf(gB);
      float hA = sigm(oA)*tanhf(cnA);
      float hB = sigm(oB)*tanhf(cnB);
      c0r = cnA; c1r = cnB;
      hp = (unsigned)f2b(hA) | ((unsigned)f2b(hB) << 16);
      if (t < 63){
        __hip_atomic_store((unsigned*)(hout + pb*1024 + hcol), hp,
                           __ATOMIC_RELAXED, __HIP_MEMORY_SCOPE_AGENT);
      } else {
        h_out[pb*1024 + hcol] = hA;  h_out[pb*1024 + hcol + 1] = hB;
        c_out[pb*1024 + hcol] = cnA; c_out[pb*1024 + hcol + 1] = cnB;
      }
    }
    if (t < 63){
      asm volatile("s_waitcnt vmcnt(0)" ::: "memory");
      __syncthreads();           // whole block's h stores drained; gbuf reads done
      if (tid == 0)
        __hip_atomic_store(flags + g*32, t+1, __ATOMIC_RELAXED, __HIP_MEMORY_SCOPE_AGENT);
    }
    // concat store AFTER flag publish: its ack flies under the next step
    *(unsigned*)(concat + ((size_t)(t*32 + pb))*2048 + hcol) = hp;
  }
}

// ---------------- attention: 8 timesteps per block (ctx reuse x8) ----------
__global__ __launch_bounds__(256) void k_attn(const u16* __restrict__ ctx,   // [32][64][1024] bf16
                                              u16* __restrict__ concat){     // [2048][2048]
  int bid = blockIdx.x;
  int b = bid & 31, tg = bid >> 5;
  int tid = threadIdx.x, lane = tid & 63, w = tid >> 6;
  __shared__ float hsh[8][1024];
  __shared__ float sc[8][64];
#pragma unroll
  for (int i = 0; i < 8; ++i){
    int row = (tg*8 + i)*32 + b;
    const unsigned* hr = (const unsigned*)(concat + (size_t)row*2048);
    unsigned v0 = hr[tid], v1 = hr[tid + 256];
    hsh[i][tid*2]       = b2f((u16)(v0 & 0xffff));
    hsh[i][tid*2+1]     = b2f((u16)(v0 >> 16));
    hsh[i][512+tid*2]   = b2f((u16)(v1 & 0xffff));
    hsh[i][512+tid*2+1] = b2f((u16)(v1 >> 16));
  }
  __syncthreads();
  const u16* cb = ctx + (size_t)b*65536;
  for (int sl = 0; sl < 16; ++sl){
    int s = w*16 + sl;
    const u16* cr = cb + (size_t)s*1024 + lane*16;
    float cv[16];
#pragma unroll
    for (int k = 0; k < 16; ++k) cv[k] = b2f(cr[k]);
#pragma unroll
    for (int i = 0; i < 8; ++i){
      float a = 0.f;
#pragma unroll
      for (int k = 0; k < 16; ++k) a += cv[k] * hsh[i][lane*16 + k];
#pragma unroll
      for (int off = 32; off; off >>= 1) a += __shfl_xor(a, off);
      if (lane == 0) sc[i][s] = a;
    }
  }
  __syncthreads();
  for (int r = w; r < 8; r += 4){
    float x = sc[r][lane];
    float mx = x;
#pragma unroll
    for (int off = 32; off; off >>= 1) mx = fmaxf(mx, __shfl_xor(mx, off));
    float p = expf(x - mx);
    float sum = p;
#pragma unroll
    for (int off = 32; off; off >>= 1) sum += __shfl_xor(sum, off);
    sc[r][lane] = p / sum;
  }
  __syncthreads();
  float4 acc8[8];
#pragma unroll
  for (int i = 0; i < 8; ++i) acc8[i] = make_float4(0.f, 0.f, 0.f, 0.f);
  for (int s = 0; s < 64; ++s){
    const u16* cr = cb + (size_t)s*1024 + tid*4;
    float cx = b2f(cr[0]), cy = b2f(cr[1]), cz = b2f(cr[2]), cw = b2f(cr[3]);
#pragma unroll
    for (int i = 0; i < 8; ++i){
      float a = sc[i][s];
      acc8[i].x += a*cx; acc8[i].y += a*cy; acc8[i].z += a*cz; acc8[i].w += a*cw;
    }
  }
#pragma unroll
  for (int i = 0; i < 8; ++i){
    int row = (tg*8 + i)*32 + b;
    u64 packed = (u64)f2b(acc8[i].x) | ((u64)f2b(acc8[i].y) << 16)
               | ((u64)f2b(acc8[i].z) << 32) | ((u64)f2b(acc8[i].w) << 48);
    *(u64*)(concat + (size_t)row*2048 + 1024 + tid*4) = packed;
  }
}

// ---------------- merged: per-row lse + log-softmax output -----------------
__global__ __launch_bounds__(256) void k_fsub(
    const float* __restrict__ pp, const u16* __restrict__ lb,
    float* __restrict__ out, int npart)
{
  int row = blockIdx.x;
  int tid = threadIdx.x, lane = tid & 63, w = tid >> 6;
  __shared__ float ws4[4];
  const float* p = pp + (size_t)row*npart;
  float s = 0.f;
  for (int i = tid; i < npart; i += 256) s += p[i];
#pragma unroll
  for (int off = 32; off; off >>= 1) s += __shfl_xor(s, off);
  if (lane == 0) ws4[w] = s;
  __syncthreads();
  float l = logf(ws4[0] + ws4[1] + ws4[2] + ws4[3]);
  const uint4* src = (const uint4*)(lb + (size_t)row*32000);
  float4* dst = (float4*)(out + (size_t)row*32000);
  for (int gi = tid; gi < 4000; gi += 256){
    uint4 v = src[gi];
    float4 r0, r1;
    r0.x = b2f((u16)(v.x & 0xffff)) - l;  r0.y = b2f((u16)(v.x >> 16)) - l;
    r0.z = b2f((u16)(v.y & 0xffff)) - l;  r0.w = b2f((u16)(v.y >> 16)) - l;
    r1.x = b2f((u16)(v.z & 0xffff)) - l;  r1.y = b2f((u16)(v.z >> 16)) - l;
    r1.z = b2f((u16)(v.w & 0xffff)) - l;  r1.w = b2f((u16)(v.w >> 16)) - l;
    dst[gi*2]   = r0;
    dst[gi*2+1] = r1;
  }
}

// --------------------------------------------------------------------------
extern "C" void kernel_launch(void* const* d_in, const int* in_sizes, int n_in,
                              void* d_out, int out_size, void* d_ws, size_t ws_size,
                              hipStream_t stream) {
  const int*   x_seq   = (const int*)  d_in[0];
  const float* h_in    = (const float*)d_in[1];
  const float* c_in    = (const float*)d_in[2];
  const float* context = (const float*)d_in[3];
  const float* emb     = (const float*)d_in[4];
  const float* W_ih    = (const float*)d_in[5];
  const float* W_hh    = (const float*)d_in[6];
  const float* b_ih    = (const float*)d_in[7];
  const float* b_hh    = (const float*)d_in[8];
  const float* W_a     = (const float*)d_in[9];
  const float* b_a     = (const float*)d_in[10];
  const float* W_o     = (const float*)d_in[11];
  const float* b_o     = (const float*)d_in[12];
  float* out = (float*)d_out;

  char* ws = (char*)d_ws;
  size_t off = 0;
  auto alloc = [&](size_t bytes)->void*{ void* p = ws + off; off += (bytes + 255) & ~(size_t)255; return p; };
  u16* W_ih_b = (u16*)alloc((size_t)4096*512*2);
  u16* W_hh_b = (u16*)alloc((size_t)4096*1024*2);
  u16* W_a_b  = (u16*)alloc((size_t)1024*2048*2);
  u16* W_o_b  = (u16*)alloc((size_t)32000*1024*2);
  u16* ctx_b  = (u16*)alloc((size_t)32*64*1024*2);
  float* bias4 = (float*)alloc(4096*4);
  u16* e_seq  = (u16*)alloc((size_t)2048*512*2);
  u16* pre    = (u16*)alloc((size_t)2048*4096*2);
  u16* concat = (u16*)alloc((size_t)2048*2048*2);
  u16* a_seq  = (u16*)alloc((size_t)2048*1024*2);
  u16* hb0    = (u16*)alloc(32768*2);
  u16* hb1    = (u16*)alloc(32768*2);
  float* pp   = (float*)alloc((size_t)2048*500*4);
  int* flags  = (int*)alloc(8192);     // 64 ranks x 128B line
  u16* logits_b = (u16*)alloc((size_t)2048*32000*2);

  // prep: W_ih/W_hh f2b + bias4 + h-init + embedding gather (one launch)
  k_prep<<<512, 256, 0, stream>>>(W_ih, W_ih_b, W_hh, W_hh_b,
                                  b_ih, b_hh, bias4, h_in, hb0,
                                  x_seq, emb, e_seq);

  // pre_ih = e @ W_ih^T + (b_ih + b_hh)   [2048 x 4096] bf16 (128^2, 512 blk)
  gemm_bt<0><<<16*32, 256, 0, stream>>>(e_seq, W_ih_b, bias4, pre, 512, 4096, 16, nullptr);

  // fused: LSTM recurrence (blocks 0..63) + streaming f2b (blocks 64..255)
  hipMemsetAsync(flags, 0, 8192, stream);
  k_fused<<<256, 256, 0, stream>>>(pre, W_hh_b, c_in, hb0, hb1, concat,
                                   out + 65536000, out + 65536000 + 32768, flags,
                                   W_o, W_o_b, W_a, W_a_b, context, ctx_b);

  // attention: 256 blocks, 8 timesteps each -> concat[:,1024:2048]
  k_attn<<<256, 256, 0, stream>>>(ctx_b, concat);

  // a = tanh(concat @ W_a^T + b_a)  [2048 x 1024] bf16 (128^2 tile)
  gemm_bt<1><<<16*8, 256, 0, stream>>>(concat, W_a_b, b_a, a_seq, 2048, 1024, 16, nullptr);

  // logits = a @ W_o^T + b_o  [2048 x 32000] bf16 + sumexp partials
  // (256^2 tile, 32x32x16 MFMA, reg-staged conflict-free LDS)
  gemm256<3><<<8*125, 512, 0, stream>>>(a_seq, W_o_b, b_o, logits_b, 1024, 32000, 8, pp);

  // merged lse + log_softmax -> fp32 out (one block per row)
  k_fsub<<<2048, 256, 0, stream>>>(pp, logits_b, out, 500);
}

// Round 20
// 720.697 us; speedup vs baseline: 1.0325x; 1.0325x over previous
//
#include <hip/hip_runtime.h>
#include <math.h>

typedef unsigned short u16;
typedef unsigned long long u64;
typedef __attribute__((ext_vector_type(4))) float f32x4;
typedef __attribute__((ext_vector_type(16))) float f32x16;
typedef __attribute__((ext_vector_type(8))) __bf16 bf16x8;

#define GLDS16(g, l) __builtin_amdgcn_global_load_lds(                        \
    (const __attribute__((address_space(1))) void*)(g),                       \
    (__attribute__((address_space(3))) void*)(l), 16, 0, 0)

__device__ __forceinline__ u16 f2b(float x){
  unsigned u = __float_as_uint(x);
  u = (u + 0x7FFFu + ((u >> 16) & 1u)) >> 16;
  return (u16)u;
}
__device__ __forceinline__ float b2f(u16 u){ return __uint_as_float(((unsigned)u) << 16); }
__device__ __forceinline__ f32x4 zero4(){ f32x4 v; v[0]=0.f; v[1]=0.f; v[2]=0.f; v[3]=0.f; return v; }
__device__ __forceinline__ float sigm(float x){ return 1.f/(1.f+expf(-x)); }

// ---------------- combined prep: f2b(W_ih), f2b(W_hh), bias4, init, gather --
__global__ __launch_bounds__(256) void k_prep(
    const float* __restrict__ W_ih, u16* __restrict__ W_ih_b,
    const float* __restrict__ W_hh, u16* __restrict__ W_hh_b,
    const float* __restrict__ bih, const float* __restrict__ bhh,
    float* __restrict__ b4,
    const float* __restrict__ h_in, u16* __restrict__ hb0,
    const int* __restrict__ x, const float* __restrict__ emb,
    u16* __restrict__ e_seq)
{
  int g = blockIdx.x, tid = threadIdx.x;
  if (g < 128){
    size_t base = ((size_t)g*256 + tid)*4;
    size_t stride = (size_t)128*256*4;
    for (size_t i = base; i < 2097152UL; i += stride){
      float4 v = *(const float4*)(W_ih + i);
      W_ih_b[i] = f2b(v.x); W_ih_b[i+1] = f2b(v.y);
      W_ih_b[i+2] = f2b(v.z); W_ih_b[i+3] = f2b(v.w);
    }
    for (size_t i = base; i < 4194304UL; i += stride){
      float4 v = *(const float4*)(W_hh + i);
      W_hh_b[i] = f2b(v.x); W_hh_b[i+1] = f2b(v.y);
      W_hh_b[i+2] = f2b(v.z); W_hh_b[i+3] = f2b(v.w);
    }
  } else if (g < 136){
    int i = (g - 128)*256 + tid;            // 0..2047
    b4[i*2]   = bih[i*2]   + bhh[i*2];
    b4[i*2+1] = bih[i*2+1] + bhh[i*2+1];
#pragma unroll
    for (int k = 0; k < 16; ++k){
      int idx = i*16 + k;
      hb0[idx] = f2b(h_in[idx]);
    }
  } else {
    for (int row = g - 136; row < 2048; row += 376){
      int xi = x[row];
      const float* er = emb + (size_t)xi*512;
      u16* dr = e_seq + (size_t)row*512;
      for (int k = tid; k < 512; k += 256) dr[k] = f2b(er[k]);
    }
  }
}

// ---------------- 256x256 tile GEMM, 32x32x16 MFMA (round-18 champion) -----
// GLDS staging, counted vmcnt(8) + raw barriers, octet XOR swizzle both
// sides, setprio, per-wave q-quadrant rotation.
// C/D layout (verified): col=lane&31, row=(r&3)+8(r>>2)+4*hi.
template<int EPI>
__global__ __launch_bounds__(512, 1) void gemm256(
    const u16* __restrict__ A, const u16* __restrict__ B,
    const float* __restrict__ bias, u16* __restrict__ C,
    int K, int ldc, int nmt, float* __restrict__ pp)
{
  __shared__ u16 sA[2][256*64];
  __shared__ u16 sB[2][256*64];
  int nwg = gridDim.x;                 // multiple of 8
  int qq = nwg >> 3;
  int xcd = blockIdx.x & 7, idx = blockIdx.x >> 3;
  int wg = xcd*qq + idx;               // bijective XCD chunking
  int mt = wg % nmt, nt = wg / nmt;    // mt fast: consecutive blocks share B
  int m0 = mt*256, n0 = nt*256;
  int tid = threadIdx.x, lane = tid & 63, w = tid >> 6;
  int wr = w >> 2, wc = w & 3;         // wave grid 2(M) x 4(N)
  int l31 = lane & 31, hi = lane >> 5;
  int qr = (w & 1) << 1;               // q rotation per wave parity

  const u16* gA[4]; const u16* gB[4]; int ld4[4];
  {
    int srl = lane >> 3, soc = lane & 7;
#pragma unroll
    for (int j = 0; j < 4; ++j){
      int row = w*8 + 64*j + srl;
      int oc = soc ^ (row & 7);
      gA[j] = A + (size_t)(m0 + row)*K + oc*8;
      gB[j] = B + (size_t)(n0 + row)*K + oc*8;
      ld4[j] = (w*8 + 64*j) * 64;      // u16 units, wave-uniform
    }
  }
#define STG(buf, k0) do{                                                      \
    GLDS16(gA[0] + (k0), &sA[buf][ld4[0]]);                                   \
    GLDS16(gB[0] + (k0), &sB[buf][ld4[0]]);                                   \
    GLDS16(gA[1] + (k0), &sA[buf][ld4[1]]);                                   \
    GLDS16(gB[1] + (k0), &sB[buf][ld4[1]]);                                   \
    GLDS16(gA[2] + (k0), &sA[buf][ld4[2]]);                                   \
    GLDS16(gB[2] + (k0), &sB[buf][ld4[2]]);                                   \
    GLDS16(gA[3] + (k0), &sA[buf][ld4[3]]);                                   \
    GLDS16(gB[3] + (k0), &sB[buf][ld4[3]]);                                   \
  }while(0)

  f32x16 acc[4][2];
#pragma unroll
  for (int m = 0; m < 4; ++m)
#pragma unroll
    for (int n = 0; n < 2; ++n)
#pragma unroll
      for (int r = 0; r < 16; ++r) acc[m][n][r] = 0.f;

  int T = K >> 6;
  STG(0, 0);
  int cur = 0;
  for (int t = 0; t < T; ++t){
    if (t+1 < T){
      STG(cur^1, (t+1) << 6);
      asm volatile("s_waitcnt vmcnt(8)" ::: "memory");   // tile t staged
    } else {
      asm volatile("s_waitcnt vmcnt(0)" ::: "memory");
    }
    __builtin_amdgcn_s_barrier();                        // raw: no drain
    asm volatile("" ::: "memory");
    __builtin_amdgcn_s_setprio(1);
#pragma unroll
    for (int qi = 0; qi < 4; ++qi){
      int q = (qi + qr) & 3;
      int ko0 = q*2 + hi;
      bf16x8 av[4], bv[2];
#pragma unroll
      for (int m = 0; m < 4; ++m){
        int row = wr*128 + m*32 + l31;
        av[m] = *(const bf16x8*)&sA[cur][row*64 + ((ko0 ^ (row & 7))*8)];
      }
#pragma unroll
      for (int n = 0; n < 2; ++n){
        int brow = wc*64 + n*32 + l31;
        bv[n] = *(const bf16x8*)&sB[cur][brow*64 + ((ko0 ^ (brow & 7))*8)];
      }
#pragma unroll
      for (int m = 0; m < 4; ++m)
#pragma unroll
        for (int n = 0; n < 2; ++n)
          acc[m][n] = __builtin_amdgcn_mfma_f32_32x32x16_bf16(av[m], bv[n], acc[m][n], 0, 0, 0);
    }
    __builtin_amdgcn_s_setprio(0);
    asm volatile("" ::: "memory");
    __builtin_amdgcn_s_barrier();                        // raw: reads of cur done
    cur ^= 1;
  }
#undef STG

#pragma unroll
  for (int m = 0; m < 4; ++m){
    float es16[16];
    if (EPI == 3){
#pragma unroll
      for (int r = 0; r < 16; ++r) es16[r] = 0.f;
    }
#pragma unroll
    for (int n = 0; n < 2; ++n){
      int ccol = n0 + wc*64 + n*32 + l31;
      float bv2 = bias ? bias[ccol] : 0.f;
#pragma unroll
      for (int r = 0; r < 16; ++r){
        int crow = m0 + wr*128 + m*32 + (r & 3) + 8*(r >> 2) + 4*hi;
        float v = acc[m][n][r] + bv2;
        C[(size_t)crow*ldc + ccol] = f2b(v);
        if (EPI == 3) es16[r] += expf(v);
      }
    }
    if (EPI == 3){
      int npart = (nwg / nmt) * 4;
#pragma unroll
      for (int r = 0; r < 16; ++r){
        float s = es16[r];
        s += __shfl_xor(s, 1); s += __shfl_xor(s, 2); s += __shfl_xor(s, 4);
        s += __shfl_xor(s, 8); s += __shfl_xor(s, 16);
        es16[r] = s;
      }
      if (l31 == 0){
#pragma unroll
        for (int r = 0; r < 16; ++r){
          int row = m0 + wr*128 + m*32 + (r & 3) + 8*(r >> 2) + 4*hi;
          pp[(size_t)row*npart + nt*4 + wc] = es16[r];
        }
      }
    }
  }
}

// ---------------- 128x128 GEMM (round-8 version) ---------------------------
template<int EPI>
__global__ __launch_bounds__(256) void gemm_bt(
    const u16* __restrict__ A, const u16* __restrict__ B,
    const float* __restrict__ bias, void* __restrict__ Cv,
    int K, int ldc, int nmt, float* __restrict__ pp)
{
  __shared__ u16 sA[2][128*32];
  __shared__ u16 sB[2][128*32];
  int nwg = gridDim.x;
  int qq = nwg >> 3, rr8 = nwg & 7;
  int xcd = blockIdx.x & 7, idx = blockIdx.x >> 3;
  int wg = (xcd < rr8 ? xcd*(qq+1) : rr8*(qq+1) + (xcd - rr8)*qq) + idx;
  int mt = wg % nmt, nt = wg / nmt;
  int m0 = mt*128, n0 = nt*128;
  int tid = threadIdx.x, lane = tid & 63, wid = tid >> 6;
  int q = lane & 3, rr = lane >> 2;
  int c0 = wid*2, c1 = wid*2+1;
  int sq = rr & 3;
  const u16* gA0 = A + (size_t)(m0 + c0*16 + rr)*K + ((q ^ sq)*8);
  const u16* gA1 = A + (size_t)(m0 + c1*16 + rr)*K + ((q ^ sq)*8);
  const u16* gB0 = B + (size_t)(n0 + c0*16 + rr)*K + ((q ^ sq)*8);
  const u16* gB1 = B + (size_t)(n0 + c1*16 + rr)*K + ((q ^ sq)*8);
  f32x4 acc[4][4];
#pragma unroll
  for (int m=0;m<4;++m)
#pragma unroll
    for (int n=0;n<4;++n) acc[m][n] = zero4();
  int wr = wid >> 1, wc = wid & 1;
  int lr = lane & 15, ks = lane >> 4;
  int rdoff = (ks ^ (lr & 3)) * 8;

#define STAGEG(buf, k0) do{                                                   \
    GLDS16(gA0 + (k0), sA[buf] + c0*512);                                     \
    GLDS16(gA1 + (k0), sA[buf] + c1*512);                                     \
    GLDS16(gB0 + (k0), sB[buf] + c0*512);                                     \
    GLDS16(gB1 + (k0), sB[buf] + c1*512);                                     \
  }while(0)

  STAGEG(0, 0);
  asm volatile("s_waitcnt vmcnt(0)" ::: "memory");
  __syncthreads();
  int cur = 0;
  for (int k0 = 0; k0 < K; k0 += 32){
    if (k0 + 32 < K) STAGEG(cur^1, k0 + 32);
    bf16x8 af[4], bfr[4];
#pragma unroll
    for (int m=0;m<4;++m) af[m]  = *(const bf16x8*)&sA[cur][(wr*64 + m*16 + lr)*32 + rdoff];
#pragma unroll
    for (int n=0;n<4;++n) bfr[n] = *(const bf16x8*)&sB[cur][(wc*64 + n*16 + lr)*32 + rdoff];
#pragma unroll
    for (int m=0;m<4;++m)
#pragma unroll
      for (int n=0;n<4;++n)
        acc[m][n] = __builtin_amdgcn_mfma_f32_16x16x32_bf16(af[m], bfr[n], acc[m][n], 0, 0, 0);
    asm volatile("s_waitcnt vmcnt(0)" ::: "memory");
    __syncthreads();
    cur ^= 1;
  }
#undef STAGEG

#pragma unroll
  for (int m=0;m<4;++m){
    int crow = m0 + wr*64 + m*16 + ks*4;
#pragma unroll
    for (int n=0;n<4;++n){
      int ccol = n0 + wc*64 + n*16 + lr;
      float bv = bias ? bias[ccol] : 0.f;
#pragma unroll
      for (int r=0;r<4;++r){
        float v = acc[m][n][r] + bv;
        if (EPI == 1) v = tanhf(v);
        ((u16*)Cv)[(size_t)(crow + r)*ldc + ccol] = f2b(v);
      }
    }
  }
}

// ---------------- fused: LSTM (64 blocks) + streaming f2b helpers ---------
// (round-18 champion body, unchanged)
__global__ __launch_bounds__(256, 1) void k_fused(
    const u16* __restrict__ pre,   // [2048][4096] bf16
    const u16* __restrict__ Whh,   // [4096][1024] bf16
    const float* __restrict__ c_in,// [32][1024] fp32
    u16* __restrict__ h0buf,       // [32][1024] bf16 ping (holds h_0)
    u16* __restrict__ h1buf,       // pong
    u16* __restrict__ concat,      // [2048][2048] bf16; cols 0..1023 <- h_t
    float* __restrict__ h_out,     // [32][1024] fp32 final h
    float* __restrict__ c_out,     // [32][1024] fp32 final c
    int* __restrict__ flags,       // [64*32] zeroed per launch (128B/rank)
    const float* __restrict__ W_o, u16* __restrict__ W_o_b,
    const float* __restrict__ W_a, u16* __restrict__ W_a_b,
    const float* __restrict__ ctx, u16* __restrict__ ctx_b)
{
  __shared__ u16 sA[32*1024];
  int tid = threadIdx.x;
  int g = blockIdx.x;

  if (g >= 64){
    int hb2 = g - 64;                        // 0..191
    size_t stride = (size_t)192*256*4;
    size_t base = ((size_t)hb2*256 + tid)*4;
    for (size_t i = base; i < 32768000UL; i += stride){
      float4 v = *(const float4*)(W_o + i);
      u16 o0 = f2b(v.x), o1 = f2b(v.y), o2 = f2b(v.z), o3 = f2b(v.w);
      W_o_b[i] = o0; W_o_b[i+1] = o1; W_o_b[i+2] = o2; W_o_b[i+3] = o3;
    }
    for (size_t i = base; i < 2097152UL; i += stride){
      float4 v = *(const float4*)(W_a + i);
      u16 o0 = f2b(v.x), o1 = f2b(v.y), o2 = f2b(v.z), o3 = f2b(v.w);
      W_a_b[i] = o0; W_a_b[i+1] = o1; W_a_b[i+2] = o2; W_a_b[i+3] = o3;
    }
    for (size_t i = base; i < 2097152UL; i += stride){
      float4 v = *(const float4*)(ctx + i);
      u16 o0 = f2b(v.x), o1 = f2b(v.y), o2 = f2b(v.z), o3 = f2b(v.w);
      ctx_b[i] = o0; ctx_b[i+1] = o1; ctx_b[i+2] = o2; ctx_b[i+3] = o3;
    }
    return;
  }

  int w = tid >> 6, lane = tid & 63;
  int n = (g << 2) + w;            // 0..255
  int lr = lane & 15, ks = lane >> 4;

  bf16x8 breg[32];
  {
    const u16* wrow = Whh + (size_t)((lr>>2)*1024 + (n<<2) + (lr&3))*1024 + ks*8;
#pragma unroll
    for (int q2 = 0; q2 < 32; ++q2) breg[q2] = *(const bf16x8*)(wrow + q2*32);
  }
  int pb = lane & 31, dp = lane >> 5;
  int hcol = (n << 2) + dp*2;
  float c0r = c_in[pb*1024 + hcol];
  float c1r = c_in[pb*1024 + hcol + 1];

  int srow = tid >> 3, tc = tid & 7;   // staging: 8 threads per h row, 256B each
  float* gbuf = (float*)sA + w*544;    // per-wave 32x17-stride gate buffer
  const int* myflag = flags + lane*32; // one 128B line per rank

  for (int t = 0; t < 64; ++t){
    const u16* hin = (t & 1) ? h1buf : h0buf;
    u16* hout      = (t & 1) ? h0buf : h1buf;
    const u16* prow = pre + (size_t)(t*32)*4096 + (lr>>2)*1024 + (n<<2) + (lr&3);
    u16 pr0[4], pr1[4];
#pragma unroll
    for (int r2 = 0; r2 < 4; ++r2){
      int b0 = (ks<<2) + r2;
      pr0[r2] = prow[(size_t)b0*4096];
      pr1[r2] = prow[(size_t)(16+b0)*4096];
    }
    if (t && w == 0){
      int cap = 0;
      while (__hip_atomic_load(myflag, __ATOMIC_RELAXED, __HIP_MEMORY_SCOPE_AGENT) < t
             && ++cap < (1<<24))
        __builtin_amdgcn_s_sleep(1);
    }
    __syncthreads();             // wave 0 confirmed all 64 flags >= t
    u64 t0[16], t1[16];
#pragma unroll
    for (int j = 0; j < 16; ++j){
      const u64* src = (const u64*)(hin + srow*1024 + tc*8 + j*64);
      t0[j] = __hip_atomic_load(src,     __ATOMIC_RELAXED, __HIP_MEMORY_SCOPE_AGENT);
      t1[j] = __hip_atomic_load(src + 1, __ATOMIC_RELAXED, __HIP_MEMORY_SCOPE_AGENT);
    }
#pragma unroll
    for (int j = 0; j < 8; ++j){
      int kc = tc*8 + j*64;
      int dk = kc ^ ((srow & 7) << 3);
      ulonglong2 v2; v2.x = t0[j]; v2.y = t1[j];
      *(ulonglong2*)&sA[srow*1024 + dk] = v2;
    }
    __syncthreads();
    f32x4 acc0 = zero4(), acc1 = zero4();
#pragma unroll
    for (int q2 = 0; q2 < 16; ++q2){
      int ka = ((q2<<5) + (ks<<3)) ^ ((lr & 7) << 3);
      bf16x8 a0 = *(const bf16x8*)&sA[lr*1024 + ka];
      bf16x8 a1 = *(const bf16x8*)&sA[(16+lr)*1024 + ka];
      acc0 = __builtin_amdgcn_mfma_f32_16x16x32_bf16(a0, breg[q2], acc0, 0, 0, 0);
      acc1 = __builtin_amdgcn_mfma_f32_16x16x32_bf16(a1, breg[q2], acc1, 0, 0, 0);
    }
#pragma unroll
    for (int j = 8; j < 16; ++j){
      int kc = tc*8 + j*64;
      int dk = kc ^ ((srow & 7) << 3);
      ulonglong2 v2; v2.x = t0[j]; v2.y = t1[j];
      *(ulonglong2*)&sA[srow*1024 + dk] = v2;
    }
    __syncthreads();
#pragma unroll
    for (int q2 = 16; q2 < 32; ++q2){
      int ka = ((q2<<5) + (ks<<3)) ^ ((lr & 7) << 3);
      bf16x8 a0 = *(const bf16x8*)&sA[lr*1024 + ka];
      bf16x8 a1 = *(const bf16x8*)&sA[(16+lr)*1024 + ka];
      acc0 = __builtin_amdgcn_mfma_f32_16x16x32_bf16(a0, breg[q2], acc0, 0, 0, 0);
      acc1 = __builtin_amdgcn_mfma_f32_16x16x32_bf16(a1, breg[q2], acc1, 0, 0, 0);
    }
    __syncthreads();
#pragma unroll
    for (int r2 = 0; r2 < 4; ++r2){
      int b0 = (ks<<2) + r2;
      gbuf[b0*17 + lr]      = acc0[r2] + b2f(pr0[r2]);
      gbuf[(16+b0)*17 + lr] = acc1[r2] + b2f(pr1[r2]);
    }
    __syncthreads();
    unsigned hp;
    {
      int d0 = dp*2;
      float iA = gbuf[pb*17 + d0],      iB = gbuf[pb*17 + d0 + 1];
      float fA = gbuf[pb*17 + 4 + d0],  fB = gbuf[pb*17 + 5 + d0];
      float gA = gbuf[pb*17 + 8 + d0],  gB = gbuf[pb*17 + 9 + d0];
      float oA = gbuf[pb*17 + 12 + d0], oB = gbuf[pb*17 + 13 + d0];
      float cnA = sigm(fA)*c0r + sigm(iA)*tanhf(gA);
      float cnB = sigm(fB)*c1r + sigm(iB)*tanhf(gB);
      float hA = sigm(oA)*tanhf(cnA);
      float hB = sigm(oB)*tanhf(cnB);
      c0r = cnA; c1r = cnB;
      hp = (unsigned)f2b(hA) | ((unsigned)f2b(hB) << 16);
      if (t < 63){
        __hip_atomic_store((unsigned*)(hout + pb*1024 + hcol), hp,
                           __ATOMIC_RELAXED, __HIP_MEMORY_SCOPE_AGENT);
      } else {
        h_out[pb*1024 + hcol] = hA;  h_out[pb*1024 + hcol + 1] = hB;
        c_out[pb*1024 + hcol] = cnA; c_out[pb*1024 + hcol + 1] = cnB;
      }
    }
    if (t < 63){
      asm volatile("s_waitcnt vmcnt(0)" ::: "memory");
      __syncthreads();           // whole block's h stores drained; gbuf reads done
      if (tid == 0)
        __hip_atomic_store(flags + g*32, t+1, __ATOMIC_RELAXED, __HIP_MEMORY_SCOPE_AGENT);
    }
    // concat store AFTER flag publish: its ack flies under the next step
    *(unsigned*)(concat + ((size_t)(t*32 + pb))*2048 + hcol) = hp;
  }
}

// ---------------- attention: 8 timesteps per block (ctx reuse x8) ----------
__global__ __launch_bounds__(256) void k_attn(const u16* __restrict__ ctx,   // [32][64][1024] bf16
                                              u16* __restrict__ concat){     // [2048][2048]
  int bid = blockIdx.x;
  int b = bid & 31, tg = bid >> 5;
  int tid = threadIdx.x, lane = tid & 63, w = tid >> 6;
  __shared__ float hsh[8][1024];
  __shared__ float sc[8][64];
#pragma unroll
  for (int i = 0; i < 8; ++i){
    int row = (tg*8 + i)*32 + b;
    const unsigned* hr = (const unsigned*)(concat + (size_t)row*2048);
    unsigned v0 = hr[tid], v1 = hr[tid + 256];
    hsh[i][tid*2]       = b2f((u16)(v0 & 0xffff));
    hsh[i][tid*2+1]     = b2f((u16)(v0 >> 16));
    hsh[i][512+tid*2]   = b2f((u16)(v1 & 0xffff));
    hsh[i][512+tid*2+1] = b2f((u16)(v1 >> 16));
  }
  __syncthreads();
  const u16* cb = ctx + (size_t)b*65536;
  for (int sl = 0; sl < 16; ++sl){
    int s = w*16 + sl;
    const u16* cr = cb + (size_t)s*1024 + lane*16;
    float cv[16];
#pragma unroll
    for (int k = 0; k < 16; ++k) cv[k] = b2f(cr[k]);
#pragma unroll
    for (int i = 0; i < 8; ++i){
      float a = 0.f;
#pragma unroll
      for (int k = 0; k < 16; ++k) a += cv[k] * hsh[i][lane*16 + k];
#pragma unroll
      for (int off = 32; off; off >>= 1) a += __shfl_xor(a, off);
      if (lane == 0) sc[i][s] = a;
    }
  }
  __syncthreads();
  for (int r = w; r < 8; r += 4){
    float x = sc[r][lane];
    float mx = x;
#pragma unroll
    for (int off = 32; off; off >>= 1) mx = fmaxf(mx, __shfl_xor(mx, off));
    float p = expf(x - mx);
    float sum = p;
#pragma unroll
    for (int off = 32; off; off >>= 1) sum += __shfl_xor(sum, off);
    sc[r][lane] = p / sum;
  }
  __syncthreads();
  float4 acc8[8];
#pragma unroll
  for (int i = 0; i < 8; ++i) acc8[i] = make_float4(0.f, 0.f, 0.f, 0.f);
  for (int s = 0; s < 64; ++s){
    const u16* cr = cb + (size_t)s*1024 + tid*4;
    float cx = b2f(cr[0]), cy = b2f(cr[1]), cz = b2f(cr[2]), cw = b2f(cr[3]);
#pragma unroll
    for (int i = 0; i < 8; ++i){
      float a = sc[i][s];
      acc8[i].x += a*cx; acc8[i].y += a*cy; acc8[i].z += a*cz; acc8[i].w += a*cw;
    }
  }
#pragma unroll
  for (int i = 0; i < 8; ++i){
    int row = (tg*8 + i)*32 + b;
    u64 packed = (u64)f2b(acc8[i].x) | ((u64)f2b(acc8[i].y) << 16)
               | ((u64)f2b(acc8[i].z) << 32) | ((u64)f2b(acc8[i].w) << 48);
    *(u64*)(concat + (size_t)row*2048 + 1024 + tid*4) = packed;
  }
}

// ---------------- merged: per-row lse + log-softmax output -----------------
__global__ __launch_bounds__(256) void k_fsub(
    const float* __restrict__ pp, const u16* __restrict__ lb,
    float* __restrict__ out, int npart)
{
  int row = blockIdx.x;
  int tid = threadIdx.x, lane = tid & 63, w = tid >> 6;
  __shared__ float ws4[4];
  const float* p = pp + (size_t)row*npart;
  float s = 0.f;
  for (int i = tid; i < npart; i += 256) s += p[i];
#pragma unroll
  for (int off = 32; off; off >>= 1) s += __shfl_xor(s, off);
  if (lane == 0) ws4[w] = s;
  __syncthreads();
  float l = logf(ws4[0] + ws4[1] + ws4[2] + ws4[3]);
  const uint4* src = (const uint4*)(lb + (size_t)row*32000);
  float4* dst = (float4*)(out + (size_t)row*32000);
  for (int gi = tid; gi < 4000; gi += 256){
    uint4 v = src[gi];
    float4 r0, r1;
    r0.x = b2f((u16)(v.x & 0xffff)) - l;  r0.y = b2f((u16)(v.x >> 16)) - l;
    r0.z = b2f((u16)(v.y & 0xffff)) - l;  r0.w = b2f((u16)(v.y >> 16)) - l;
    r1.x = b2f((u16)(v.z & 0xffff)) - l;  r1.y = b2f((u16)(v.z >> 16)) - l;
    r1.z = b2f((u16)(v.w & 0xffff)) - l;  r1.w = b2f((u16)(v.w >> 16)) - l;
    dst[gi*2]   = r0;
    dst[gi*2+1] = r1;
  }
}

// --------------------------------------------------------------------------
extern "C" void kernel_launch(void* const* d_in, const int* in_sizes, int n_in,
                              void* d_out, int out_size, void* d_ws, size_t ws_size,
                              hipStream_t stream) {
  const int*   x_seq   = (const int*)  d_in[0];
  const float* h_in    = (const float*)d_in[1];
  const float* c_in    = (const float*)d_in[2];
  const float* context = (const float*)d_in[3];
  const float* emb     = (const float*)d_in[4];
  const float* W_ih    = (const float*)d_in[5];
  const float* W_hh    = (const float*)d_in[6];
  const float* b_ih    = (const float*)d_in[7];
  const float* b_hh    = (const float*)d_in[8];
  const float* W_a     = (const float*)d_in[9];
  const float* b_a     = (const float*)d_in[10];
  const float* W_o     = (const float*)d_in[11];
  const float* b_o     = (const float*)d_in[12];
  float* out = (float*)d_out;

  char* ws = (char*)d_ws;
  size_t off = 0;
  auto alloc = [&](size_t bytes)->void*{ void* p = ws + off; off += (bytes + 255) & ~(size_t)255; return p; };
  u16* W_ih_b = (u16*)alloc((size_t)4096*512*2);
  u16* W_hh_b = (u16*)alloc((size_t)4096*1024*2);
  u16* W_a_b  = (u16*)alloc((size_t)1024*2048*2);
  u16* W_o_b  = (u16*)alloc((size_t)32000*1024*2);
  u16* ctx_b  = (u16*)alloc((size_t)32*64*1024*2);
  float* bias4 = (float*)alloc(4096*4);
  u16* e_seq  = (u16*)alloc((size_t)2048*512*2);
  u16* pre    = (u16*)alloc((size_t)2048*4096*2);
  u16* concat = (u16*)alloc((size_t)2048*2048*2);
  u16* a_seq  = (u16*)alloc((size_t)2048*1024*2);
  u16* hb0    = (u16*)alloc(32768*2);
  u16* hb1    = (u16*)alloc(32768*2);
  float* pp   = (float*)alloc((size_t)2048*500*4);
  int* flags  = (int*)alloc(8192);     // 64 ranks x 128B line
  u16* logits_b = (u16*)alloc((size_t)2048*32000*2);

  // prep: W_ih/W_hh f2b + bias4 + h-init + embedding gather (one launch)
  k_prep<<<512, 256, 0, stream>>>(W_ih, W_ih_b, W_hh, W_hh_b,
                                  b_ih, b_hh, bias4, h_in, hb0,
                                  x_seq, emb, e_seq);

  // pre_ih = e @ W_ih^T + (b_ih + b_hh)   [2048 x 4096] bf16 (128^2, 512 blk)
  gemm_bt<0><<<16*32, 256, 0, stream>>>(e_seq, W_ih_b, bias4, pre, 512, 4096, 16, nullptr);

  // fused: LSTM recurrence (blocks 0..63) + streaming f2b (blocks 64..255)
  hipMemsetAsync(flags, 0, 8192, stream);
  k_fused<<<256, 256, 0, stream>>>(pre, W_hh_b, c_in, hb0, hb1, concat,
                                   out + 65536000, out + 65536000 + 32768, flags,
                                   W_o, W_o_b, W_a, W_a_b, context, ctx_b);

  // attention: 256 blocks, 8 timesteps each -> concat[:,1024:2048]
  k_attn<<<256, 256, 0, stream>>>(ctx_b, concat);

  // a = tanh(concat @ W_a^T + b_a)  [2048 x 1024] bf16 (128^2 tile)
  gemm_bt<1><<<16*8, 256, 0, stream>>>(concat, W_a_b, b_a, a_seq, 2048, 1024, 16, nullptr);

  // logits = a @ W_o^T + b_o  [2048 x 32000] bf16 + sumexp partials
  // (256^2 tile, 32x32x16 MFMA, GLDS counted-vmcnt pipeline, q-rotation)
  gemm256<3><<<8*125, 512, 0, stream>>>(a_seq, W_o_b, b_o, logits_b, 1024, 32000, 8, pp);

  // merged lse + log_softmax -> fp32 out (one block per row)
  k_fsub<<<2048, 256, 0, stream>>>(pp, logits_b, out, 500);
}